// Round 4
// baseline (3249.153 us; speedup 1.0000x reference)
//
#include <hip/hip_runtime.h>
#include <hip/hip_bf16.h>

#define BB 32
#define SS 512
#define HH 512
#define VV 32000
#define EE 768
#define NC 3
#define G4 2048
#define MM (BB*SS)
#define NWG 16   // workgroups per direction in k_scan
#define SIGT (NWG*8)  // per-step signal target: 16 wgs x 8 waves

typedef __attribute__((ext_vector_type(8))) short bf16x8;
typedef __attribute__((ext_vector_type(4))) float f32x4;
typedef unsigned int u32;
typedef unsigned short u16;
typedef unsigned long long u64;
typedef __attribute__((ext_vector_type(4))) u32 u32x4;

#define MFMA(a,b,c) __builtin_amdgcn_mfma_f32_16x16x32_bf16(a,b,c,0,0,0)

static __device__ __forceinline__ u16 f2bf(float f) {
  union { float f; u32 u; } v; v.f = f;
  return (u16)((v.u + 0x7fffu + ((v.u >> 16) & 1u)) >> 16);
}
static __device__ __forceinline__ float bf2f(u16 h) {
  union { u32 u; float f; } v; v.u = ((u32)h) << 16;
  return v.f;
}
static __device__ __forceinline__ float sigm(float x) { return 1.f/(1.f+__expf(-x)); }
static __device__ __forceinline__ float tanh_f(float x) {
  x = fminf(8.f, fmaxf(-8.f, x));
  float t = __expf(2.f*x);
  return (t-1.f)/(t+1.f);
}

static __device__ __forceinline__ u32 coh_ld32(const u32* p) {
  return __hip_atomic_load(p, __ATOMIC_RELAXED, __HIP_MEMORY_SCOPE_AGENT);
}
static __device__ __forceinline__ void coh_st32(u32* p, u32 v) {
  __hip_atomic_store(p, v, __ATOMIC_RELAXED, __HIP_MEMORY_SCOPE_AGENT);
}

// ---------- prep: fp32 -> bf16 table convert ----------
__global__ void k_conv(const float* __restrict__ src, u16* __restrict__ dst, int n8) {
  int i = blockIdx.x * blockDim.x + threadIdx.x;
  if (i >= n8) return;
  const float4* s = ((const float4*)src) + (size_t)i*2;
  float4 a = s[0], b = s[1];
  u32 x = (u32)f2bf(a.x) | ((u32)f2bf(a.y) << 16);
  u32 y = (u32)f2bf(a.z) | ((u32)f2bf(a.w) << 16);
  u32 z = (u32)f2bf(b.x) | ((u32)f2bf(b.y) << 16);
  u32 w = (u32)f2bf(b.z) | ((u32)f2bf(b.w) << 16);
  ((uint4*)dst)[i] = make_uint4(x, y, z, w);
}

// ---------- prep: pack B matrix [K][N] fp32 -> MFMA fragment layout bf16 ----------
__global__ void k_pack(const float* __restrict__ src, u16* __restrict__ dst, int K, int N) {
  int tid = blockIdx.x * 256 + threadIdx.x;
  int nkf = K >> 5;
  int l = tid & 63, fi = tid >> 6;
  int kf = fi % nkf, nf = fi / nkf;
  if (nf >= (N >> 4)) return;
  int col = nf * 16 + (l & 15);
  int k0 = kf * 32 + (l >> 4) * 8;
  u32 o[4];
  #pragma unroll
  for (int j = 0; j < 4; ++j) {
    u16 lo = f2bf(src[(size_t)(k0 + 2*j) * N + col]);
    u16 hi = f2bf(src[(size_t)(k0 + 2*j + 1) * N + col]);
    o[j] = (u32)lo | ((u32)hi << 16);
  }
  *((uint4*)(dst + (size_t)tid * 8)) = make_uint4(o[0], o[1], o[2], o[3]);
}

// ---------- phase A: zx = gather(emb) @ K + bias + K_prior_row ----------
__global__ __launch_bounds__(256) void k_proj(
    const u16* __restrict__ embT, const u16* __restrict__ Bp0, const u16* __restrict__ Bp1,
    const float* __restrict__ bias0, const float* __restrict__ bias1,
    const float* __restrict__ K0, const float* __restrict__ K1,
    const int* __restrict__ ids, const int* __restrict__ prior,
    u16* __restrict__ zx0, u16* __restrict__ zx1)
{
  int mt = blockIdx.x;
  int gy = blockIdx.y;
  int dir = gy >> 4, nt = gy & 15;
  const u16* Bp = dir ? Bp1 : Bp0;
  const float* bias = dir ? bias1 : bias0;
  const float* Kp = (dir ? K1 : K0) + (size_t)EE * G4;
  u16* zx = dir ? zx1 : zx0;
  int w = threadIdx.x >> 6, l = threadIdx.x & 63;
  int m0 = mt * 128 + w * 32;
  int r0 = m0 + (l & 15);
  int id0 = ids[(r0 & 31) * SS + (r0 >> 5)];
  int id1 = ids[((r0 + 16) & 31) * SS + ((r0 + 16) >> 5)];
  const u16* a0p = embT + (size_t)id0 * EE + (l >> 4) * 8;
  const u16* a1p = embT + (size_t)id1 * EE + (l >> 4) * 8;
  f32x4 acc[2][8];
  #pragma unroll
  for (int i = 0; i < 2; ++i)
    #pragma unroll
    for (int j = 0; j < 8; ++j) acc[i][j] = (f32x4){0.f,0.f,0.f,0.f};
  const u16* bbase = Bp + ((size_t)(nt*8)*24)*512 + (size_t)l*8;
  for (int kf = 0; kf < 24; ++kf) {
    bf16x8 a0 = *(const bf16x8*)(a0p + kf*32);
    bf16x8 a1 = *(const bf16x8*)(a1p + kf*32);
    #pragma unroll
    for (int nf = 0; nf < 8; ++nf) {
      bf16x8 bv = *(const bf16x8*)(bbase + (size_t)(nf*24 + kf)*512);
      acc[0][nf] = MFMA(a0, bv, acc[0][nf]);
      acc[1][nf] = MFMA(a1, bv, acc[1][nf]);
    }
  }
  int cb = nt*128 + (l & 15);
  #pragma unroll
  for (int mi = 0; mi < 2; ++mi) {
    #pragma unroll
    for (int r = 0; r < 4; ++r) {
      int row = m0 + mi*16 + (l >> 4)*4 + r;
      int p = prior[(row & 31) * SS + (row >> 5)];
      const float* kr = Kp + (size_t)p * G4;
      u16* zr = zx + (size_t)row * G4;
      #pragma unroll
      for (int nf = 0; nf < 8; ++nf) {
        int col = cb + nf*16;
        zr[col] = f2bf(acc[mi][nf][r] + bias[col] + kr[col]);
      }
    }
  }
}

// ---------- phase B: persistent bidirectional LSTM scan ----------
// 32 wgs x 512 thr: dir = wg>>4, wgi = wg&15 (16 wgs/dir, 32 h-cols each).
// Wave w: gate w&3, col-half w>>2. h[t-1] staged cooperatively into LDS
// (conflict-free 16B-granular layout) from coherent (sc0 sc1) loads.
// Release: per-wave vmcnt ack + wave-leader relaxed fetch_add (target 128).
__global__ __launch_bounds__(512, 2) void k_scan(
    const u16* __restrict__ zxf, const u16* __restrict__ zxb,
    const u16* __restrict__ Rf, const u16* __restrict__ Rb,
    u16* __restrict__ hf, u16* __restrict__ hb,
    u32* __restrict__ cntf, u32* __restrict__ cntb)
{
  int wg = blockIdx.x, dir = wg >> 4, wgi = wg & 15;
  const u16* zx = dir ? zxb : zxf;
  const u16* Rp = dir ? Rb : Rf;
  u16* hbuf = dir ? hb : hf;
  u32* cnt = dir ? cntb : cntf;
  int tid = threadIdx.x;
  int w = tid >> 6, l = tid & 63;
  int g = w & 3, ch = w >> 2;
  int ncb = g*32 + wgi*2 + ch;  // N col-block in packed R
  bf16x8 rb[16];
  #pragma unroll
  for (int kf = 0; kf < 16; ++kf)
    rb[kf] = *(const bf16x8*)(Rp + (((size_t)ncb*16 + kf)*64 + l)*8);

  __shared__ char hstage[32*1040];       // 32 batches x 1024B, 1040B padded stride
  __shared__ float zbuf[4][32][33];

  int eb = tid >> 4;          // batch 0..31 (elementwise)
  int ec = (tid & 15) * 2;    // col pair 0..30 (elementwise)
  const char* sread0 = hstage + (l & 15)*1040 + (l >> 4)*16;
  const char* sread1 = sread0 + 16*1040;
  // staging: thread handles batch tid>>4, four 16B chunks at +0,+256,+512,+768
  char* swrite = hstage + (tid >> 4)*1040 + (tid & 15)*16;
  size_t goff = (size_t)(tid >> 4)*1024 + (tid & 15)*16;

  float c0 = 0.f, c1 = 0.f;
  for (int step = 0; step < SS; ++step) {
    int t = dir ? (SS - 1 - step) : step;
    // issue zx loads early; latency hides under poll + staging
    const u32* zxr = (const u32*)(zx + ((size_t)t*BB + eb)*G4 + wgi*32 + ec);
    u32 xi = zxr[0];
    u32 xf = zxr[256];
    u32 xg = zxr[512];
    u32 xo = zxr[768];
    f32x4 acc0 = {0.f,0.f,0.f,0.f}, acc1 = {0.f,0.f,0.f,0.f};
    if (step > 0) {
      int tp = dir ? t + 1 : t - 1;
      if (tid == 0) {
        while (coh_ld32(&cnt[tp]) < (u32)SIGT)
          __builtin_amdgcn_s_sleep(1);
      }
      __syncthreads();   // B1: poll satisfied
      const char* gsrc = (const char*)(hbuf + (size_t)tp*BB*HH) + goff;
      u32x4 s0v, s1v, s2v, s3v;
      asm volatile("global_load_dwordx4 %0, %1, off sc0 sc1" : "=v"(s0v) : "v"(gsrc)     : "memory");
      asm volatile("global_load_dwordx4 %0, %1, off sc0 sc1" : "=v"(s1v) : "v"(gsrc+256) : "memory");
      asm volatile("global_load_dwordx4 %0, %1, off sc0 sc1" : "=v"(s2v) : "v"(gsrc+512) : "memory");
      asm volatile("global_load_dwordx4 %0, %1, off sc0 sc1" : "=v"(s3v) : "v"(gsrc+768) : "memory");
      asm volatile("s_waitcnt vmcnt(0)" ::: "memory");
      __builtin_amdgcn_sched_barrier(0);  // keep ds_writes below the waitcnt
      *(u32x4*)(swrite)       = s0v;
      *(u32x4*)(swrite + 256) = s1v;
      *(u32x4*)(swrite + 512) = s2v;
      *(u32x4*)(swrite + 768) = s3v;
      __syncthreads();   // B2: stage visible
      #pragma unroll
      for (int kf = 0; kf < 16; ++kf) {
        bf16x8 a0 = *(const bf16x8*)(sread0 + kf*64);
        bf16x8 a1 = *(const bf16x8*)(sread1 + kf*64);
        acc0 = MFMA(a0, rb[kf], acc0);
        acc1 = MFMA(a1, rb[kf], acc1);
      }
    }
    int zc = ch*16 + (l & 15);
    int zb0 = (l >> 4) * 4;
    #pragma unroll
    for (int r = 0; r < 4; ++r) {
      zbuf[g][zc][zb0 + r] = acc0[r];
      zbuf[g][zc][16 + zb0 + r] = acc1[r];
    }
    __syncthreads();   // B3: gates exchanged
    float zi0 = zbuf[0][ec  ][eb] + bf2f((u16)(xi & 0xffffu));
    float zi1 = zbuf[0][ec+1][eb] + bf2f((u16)(xi >> 16));
    float zf0 = zbuf[1][ec  ][eb] + bf2f((u16)(xf & 0xffffu));
    float zf1 = zbuf[1][ec+1][eb] + bf2f((u16)(xf >> 16));
    float zg0 = zbuf[2][ec  ][eb] + bf2f((u16)(xg & 0xffffu));
    float zg1 = zbuf[2][ec+1][eb] + bf2f((u16)(xg >> 16));
    float zo0 = zbuf[3][ec  ][eb] + bf2f((u16)(xo & 0xffffu));
    float zo1 = zbuf[3][ec+1][eb] + bf2f((u16)(xo >> 16));
    c0 = sigm(zf0)*c0 + sigm(zi0)*tanh_f(zg0);
    c1 = sigm(zf1)*c1 + sigm(zi1)*tanh_f(zg1);
    float h0 = sigm(zo0)*tanh_f(c0);
    float h1 = sigm(zo1)*tanh_f(c1);
    u32 hpk = (u32)f2bf(h0) | ((u32)f2bf(h1) << 16);
    u32* hp = (u32*)(hbuf + ((size_t)t*BB + eb)*HH + wgi*32 + ec);
    coh_st32(hp, hpk);
    asm volatile("s_waitcnt vmcnt(0)" ::: "memory");  // wave's h acked at coherence point
    if (l == 0)
      __hip_atomic_fetch_add(&cnt[t], 1u, __ATOMIC_RELAXED, __HIP_MEMORY_SCOPE_AGENT);
    // no barrier: next iteration's B1 orders hstage/zbuf reuse
  }
}

// ---------- phase C: h1 = [hf|hb] @ w1 + b1 ----------
__global__ __launch_bounds__(256) void k_dense(
    const u16* __restrict__ hf, const u16* __restrict__ hb,
    const u16* __restrict__ w1p, const float* __restrict__ b1,
    u16* __restrict__ h1)
{
  int mt = blockIdx.x, nt = blockIdx.y;
  int w = threadIdx.x >> 6, l = threadIdx.x & 63;
  int m0 = mt*128 + w*32;
  int r0 = m0 + (l & 15);
  const u16* f0 = hf + (size_t)r0*HH + (l >> 4)*8;
  const u16* f1 = hf + (size_t)(r0+16)*HH + (l >> 4)*8;
  const u16* g0 = hb + (size_t)r0*HH + (l >> 4)*8;
  const u16* g1 = hb + (size_t)(r0+16)*HH + (l >> 4)*8;
  f32x4 acc[2][8];
  #pragma unroll
  for (int i = 0; i < 2; ++i)
    #pragma unroll
    for (int j = 0; j < 8; ++j) acc[i][j] = (f32x4){0.f,0.f,0.f,0.f};
  const u16* bbase = w1p + ((size_t)(nt*8)*32)*512 + (size_t)l*8;
  for (int kf = 0; kf < 32; ++kf) {
    const u16* s0 = (kf < 16) ? (f0 + kf*32) : (g0 + (kf-16)*32);
    const u16* s1 = (kf < 16) ? (f1 + kf*32) : (g1 + (kf-16)*32);
    bf16x8 a0 = *(const bf16x8*)s0;
    bf16x8 a1 = *(const bf16x8*)s1;
    #pragma unroll
    for (int nf = 0; nf < 8; ++nf) {
      bf16x8 bv = *(const bf16x8*)(bbase + (size_t)(nf*32 + kf)*512);
      acc[0][nf] = MFMA(a0, bv, acc[0][nf]);
      acc[1][nf] = MFMA(a1, bv, acc[1][nf]);
    }
  }
  int cb = nt*128 + (l & 15);
  #pragma unroll
  for (int mi = 0; mi < 2; ++mi) {
    #pragma unroll
    for (int r = 0; r < 4; ++r) {
      int row = m0 + mi*16 + (l >> 4)*4 + r;
      #pragma unroll
      for (int nf = 0; nf < 8; ++nf) {
        int col = cb + nf*16;
        h1[(size_t)row*HH + col] = f2bf(acc[mi][nf][r] + b1[col]);
      }
    }
  }
}

// ---------- phase D: logits, softmax, probs, per-block NLL partials ----------
__global__ __launch_bounds__(256) void k_out(
    const u16* __restrict__ h1, const float* __restrict__ w2, const float* __restrict__ b2,
    const int* __restrict__ labels, float* __restrict__ out, float* __restrict__ part)
{
  int w = threadIdx.x >> 6, l = threadIdx.x & 63;
  float w2r[8][3];
  #pragma unroll
  for (int i = 0; i < 8; ++i)
    #pragma unroll
    for (int c = 0; c < 3; ++c) w2r[i][c] = w2[(l*8 + i)*3 + c];
  float b20 = b2[0], b21 = b2[1], b22 = b2[2];
  float nll = 0.f;
  int base = (blockIdx.x*4 + w)*16;
  for (int r = 0; r < 16; ++r) {
    int row = base + r;
    bf16x8 hv = *(const bf16x8*)(h1 + (size_t)row*HH + l*8);
    float s0 = 0.f, s1 = 0.f, s2 = 0.f;
    #pragma unroll
    for (int i = 0; i < 8; ++i) {
      float x = bf2f((u16)hv[i]);
      s0 += x*w2r[i][0]; s1 += x*w2r[i][1]; s2 += x*w2r[i][2];
    }
    #pragma unroll
    for (int off = 32; off > 0; off >>= 1) {
      s0 += __shfl_down(s0, off);
      s1 += __shfl_down(s1, off);
      s2 += __shfl_down(s2, off);
    }
    if (l == 0) {
      float l0 = s0+b20, l1 = s1+b21, l2 = s2+b22;
      float m = fmaxf(l0, fmaxf(l1, l2));
      float e0 = __expf(l0-m), e1 = __expf(l1-m), e2 = __expf(l2-m);
      float Z = e0+e1+e2, inv = 1.f/Z;
      int b = row & 31, s = row >> 5;
      float* po = out + ((size_t)b*SS + s)*3;
      po[0] = e0*inv; po[1] = e1*inv; po[2] = e2*inv;
      int lab = labels[b*SS + s];
      float ll = (lab == 0) ? l0 : (lab == 1 ? l1 : l2);
      nll += (m + __logf(Z)) - ll;
    }
  }
  __shared__ float ps[4];
  if (l == 0) ps[w] = nll;
  __syncthreads();
  if (threadIdx.x == 0) part[blockIdx.x] = ps[0]+ps[1]+ps[2]+ps[3];
}

__global__ void k_loss(const float* __restrict__ part, float* __restrict__ out) {
  __shared__ float sh[256];
  sh[threadIdx.x] = part[threadIdx.x];
  __syncthreads();
  for (int s = 128; s > 0; s >>= 1) {
    if (threadIdx.x < s) sh[threadIdx.x] += sh[threadIdx.x + s];
    __syncthreads();
  }
  if (threadIdx.x == 0) out[(size_t)MM*NC] = sh[0] / (float)BB;
}

extern "C" void kernel_launch(void* const* d_in, const int* in_sizes, int n_in,
                              void* d_out, int out_size, void* d_ws, size_t ws_size,
                              hipStream_t stream) {
  (void)in_sizes; (void)n_in; (void)out_size;
  const float* emb = (const float*)d_in[0];
  const float* fK  = (const float*)d_in[1];
  const float* fR  = (const float*)d_in[2];
  const float* fb  = (const float*)d_in[3];
  const float* bK  = (const float*)d_in[4];
  const float* bR  = (const float*)d_in[5];
  const float* bb  = (const float*)d_in[6];
  const float* w1  = (const float*)d_in[7];
  const float* b1  = (const float*)d_in[8];
  const float* w2  = (const float*)d_in[9];
  const float* b2  = (const float*)d_in[10];
  const int* ids   = (const int*)d_in[11];
  const int* prior = (const int*)d_in[12];
  const int* labels= (const int*)d_in[13];

  size_t off = 0;
  auto take = [&](size_t bytes) -> char* {
    char* p = (char*)d_ws + off;
    off += (bytes + 255) & ~(size_t)255;
    return p;
  };
  u16* embT = (u16*)take((size_t)VV*EE*2);
  u16* Kfp  = (u16*)take((size_t)EE*G4*2);
  u16* Kbp  = (u16*)take((size_t)EE*G4*2);
  u16* Rfp  = (u16*)take((size_t)HH*G4*2);
  u16* Rbp  = (u16*)take((size_t)HH*G4*2);
  u16* w1p  = (u16*)take((size_t)(2*HH)*HH*2);
  u16* zxf  = (u16*)take((size_t)MM*G4*2);
  u16* zxb  = (u16*)take((size_t)MM*G4*2);
  u16* hf   = (u16*)take((size_t)MM*HH*2);
  u16* hb   = (u16*)take((size_t)MM*HH*2);
  u16* h1   = (u16*)take((size_t)MM*HH*2);
  u32* cnts = (u32*)take(2*SS*4);
  float* part = (float*)take(256*4);
  if (off > ws_size) return;
  u32* cntf = cnts; u32* cntb = cnts + SS;

  hipMemsetAsync(cnts, 0, 2*SS*4, stream);
  k_conv<<<12000, 256, 0, stream>>>(emb, embT, VV*EE/8);
  k_pack<<<768, 256, 0, stream>>>(fK, Kfp, EE, G4);
  k_pack<<<768, 256, 0, stream>>>(bK, Kbp, EE, G4);
  k_pack<<<512, 256, 0, stream>>>(fR, Rfp, HH, G4);
  k_pack<<<512, 256, 0, stream>>>(bR, Rbp, HH, G4);
  k_pack<<<256, 256, 0, stream>>>(w1, w1p, 2*HH, HH);
  k_proj<<<dim3(128,32), 256, 0, stream>>>(embT, Kfp, Kbp, fb, bb, fK, bK, ids, prior, zxf, zxb);
  k_scan<<<32, 512, 0, stream>>>(zxf, zxb, Rfp, Rbp, hf, hb, cntf, cntb);
  k_dense<<<dim3(128,4), 256, 0, stream>>>(hf, hb, w1p, b1, h1);
  k_out<<<256, 256, 0, stream>>>(h1, w2, b2, labels, (float*)d_out, part);
  k_loss<<<1, 256, 0, stream>>>(part, (float*)d_out);
}

// Round 6
// 2206.593 us; speedup vs baseline: 1.4725x; 1.4725x over previous
//
#include <hip/hip_runtime.h>
#include <hip/hip_bf16.h>

#define BB 32
#define SS 512
#define HH 512
#define VV 32000
#define EE 768
#define NC 3
#define G4 2048
#define MM (BB*SS)
#define SENT 0xFFFFFFFFu

typedef __attribute__((ext_vector_type(8))) short bf16x8;
typedef __attribute__((ext_vector_type(4))) float f32x4;
typedef unsigned int u32;
typedef unsigned short u16;
typedef unsigned long long u64;
typedef __attribute__((ext_vector_type(4))) u32 u32x4;

#define MFMA(a,b,c) __builtin_amdgcn_mfma_f32_16x16x32_bf16(a,b,c,0,0,0)

static __device__ __forceinline__ u16 f2bf(float f) {
  union { float f; u32 u; } v; v.f = f;
  return (u16)((v.u + 0x7fffu + ((v.u >> 16) & 1u)) >> 16);
}
static __device__ __forceinline__ float bf2f(u16 h) {
  union { u32 u; float f; } v; v.u = ((u32)h) << 16;
  return v.f;
}
static __device__ __forceinline__ float sigm(float x) { return 1.f/(1.f+__expf(-x)); }
static __device__ __forceinline__ float tanh_f(float x) {
  x = fminf(8.f, fmaxf(-8.f, x));
  float t = __expf(2.f*x);
  return (t-1.f)/(t+1.f);
}

// ---------- prep: fp32 -> bf16 table convert ----------
__global__ void k_conv(const float* __restrict__ src, u16* __restrict__ dst, int n8) {
  int i = blockIdx.x * blockDim.x + threadIdx.x;
  if (i >= n8) return;
  const float4* s = ((const float4*)src) + (size_t)i*2;
  float4 a = s[0], b = s[1];
  u32 x = (u32)f2bf(a.x) | ((u32)f2bf(a.y) << 16);
  u32 y = (u32)f2bf(a.z) | ((u32)f2bf(a.w) << 16);
  u32 z = (u32)f2bf(b.x) | ((u32)f2bf(b.y) << 16);
  u32 w = (u32)f2bf(b.z) | ((u32)f2bf(b.w) << 16);
  ((uint4*)dst)[i] = make_uint4(x, y, z, w);
}

// ---------- prep: pack B matrix [K][N] fp32 -> MFMA fragment layout bf16 ----------
__global__ void k_pack(const float* __restrict__ src, u16* __restrict__ dst, int K, int N) {
  int tid = blockIdx.x * 256 + threadIdx.x;
  int nkf = K >> 5;
  int l = tid & 63, fi = tid >> 6;
  int kf = fi % nkf, nf = fi / nkf;
  if (nf >= (N >> 4)) return;
  int col = nf * 16 + (l & 15);
  int k0 = kf * 32 + (l >> 4) * 8;
  u32 o[4];
  #pragma unroll
  for (int j = 0; j < 4; ++j) {
    u16 lo = f2bf(src[(size_t)(k0 + 2*j) * N + col]);
    u16 hi = f2bf(src[(size_t)(k0 + 2*j + 1) * N + col]);
    o[j] = (u32)lo | ((u32)hi << 16);
  }
  *((uint4*)(dst + (size_t)tid * 8)) = make_uint4(o[0], o[1], o[2], o[3]);
}

// ---------- phase A: zx = gather(emb) @ K + bias + K_prior_row ----------
__global__ __launch_bounds__(256) void k_proj(
    const u16* __restrict__ embT, const u16* __restrict__ Bp0, const u16* __restrict__ Bp1,
    const float* __restrict__ bias0, const float* __restrict__ bias1,
    const float* __restrict__ K0, const float* __restrict__ K1,
    const int* __restrict__ ids, const int* __restrict__ prior,
    u16* __restrict__ zx0, u16* __restrict__ zx1)
{
  int mt = blockIdx.x;
  int gy = blockIdx.y;
  int dir = gy >> 4, nt = gy & 15;
  const u16* Bp = dir ? Bp1 : Bp0;
  const float* bias = dir ? bias1 : bias0;
  const float* Kp = (dir ? K1 : K0) + (size_t)EE * G4;
  u16* zx = dir ? zx1 : zx0;
  int w = threadIdx.x >> 6, l = threadIdx.x & 63;
  int m0 = mt * 128 + w * 32;
  int r0 = m0 + (l & 15);
  int id0 = ids[(r0 & 31) * SS + (r0 >> 5)];
  int id1 = ids[((r0 + 16) & 31) * SS + ((r0 + 16) >> 5)];
  const u16* a0p = embT + (size_t)id0 * EE + (l >> 4) * 8;
  const u16* a1p = embT + (size_t)id1 * EE + (l >> 4) * 8;
  f32x4 acc[2][8];
  #pragma unroll
  for (int i = 0; i < 2; ++i)
    #pragma unroll
    for (int j = 0; j < 8; ++j) acc[i][j] = (f32x4){0.f,0.f,0.f,0.f};
  const u16* bbase = Bp + ((size_t)(nt*8)*24)*512 + (size_t)l*8;
  for (int kf = 0; kf < 24; ++kf) {
    bf16x8 a0 = *(const bf16x8*)(a0p + kf*32);
    bf16x8 a1 = *(const bf16x8*)(a1p + kf*32);
    #pragma unroll
    for (int nf = 0; nf < 8; ++nf) {
      bf16x8 bv = *(const bf16x8*)(bbase + (size_t)(nf*24 + kf)*512);
      acc[0][nf] = MFMA(a0, bv, acc[0][nf]);
      acc[1][nf] = MFMA(a1, bv, acc[1][nf]);
    }
  }
  int cb = nt*128 + (l & 15);
  #pragma unroll
  for (int mi = 0; mi < 2; ++mi) {
    #pragma unroll
    for (int r = 0; r < 4; ++r) {
      int row = m0 + mi*16 + (l >> 4)*4 + r;
      int p = prior[(row & 31) * SS + (row >> 5)];
      const float* kr = Kp + (size_t)p * G4;
      u16* zr = zx + (size_t)row * G4;
      #pragma unroll
      for (int nf = 0; nf < 8; ++nf) {
        int col = cb + nf*16;
        zr[col] = f2bf(acc[mi][nf][r] + bias[col] + kr[col]);
      }
    }
  }
}

// ---------- phase B: persistent bidirectional LSTM scan, sentinel-sync ----------
// 32 wgs x 512 thr: dir = wg>>4, wgi = wg&15. Wave w: gate w&3, col-half w>>2.
// NO flags/counters: h buffers are pre-filled with 0xFFFFFFFF (impossible as a
// packed sigm*tanh bf16 pair). Consumers poll the h[t-1] data itself with
// sc0 sc1 dwordx4 loads (acquire == payload, one MALL RT); producers store h
// relaxed and never wait. Only intra-wg barriers B2/B3 remain.
__global__ __launch_bounds__(512, 2) void k_scan(
    const u16* __restrict__ zxf, const u16* __restrict__ zxb,
    const u16* __restrict__ Rf, const u16* __restrict__ Rb,
    u16* __restrict__ hf, u16* __restrict__ hb)
{
  int wg = blockIdx.x, dir = wg >> 4, wgi = wg & 15;
  const u16* zx = dir ? zxb : zxf;
  const u16* Rp = dir ? Rb : Rf;
  u16* hbuf = dir ? hb : hf;
  int tid = threadIdx.x;
  int w = tid >> 6, l = tid & 63;
  int g = w & 3, ch = w >> 2;
  int ncb = g*32 + wgi*2 + ch;  // N col-block in packed R
  bf16x8 rb[16];
  #pragma unroll
  for (int kf = 0; kf < 16; ++kf)
    rb[kf] = *(const bf16x8*)(Rp + (((size_t)ncb*16 + kf)*64 + l)*8);

  __shared__ char hstage[32*1040];       // 32 batches x 1024B, 1040B padded stride
  __shared__ float zbuf[4][32][33];

  int eb = tid >> 4;          // batch 0..31 (elementwise)
  int ec = (tid & 15) * 2;    // col pair 0..30 (elementwise)
  const char* sread0 = hstage + (l & 15)*1040 + (l >> 4)*16;
  const char* sread1 = sread0 + 16*1040;
  // staging: thread handles batch tid>>4, four 16B chunks at +0,+256,+512,+768
  char* swrite = hstage + (tid >> 4)*1040 + (tid & 15)*16;
  size_t goff = (size_t)(tid >> 4)*1024 + (tid & 15)*16;

  float c0 = 0.f, c1 = 0.f;
  for (int step = 0; step < SS; ++step) {
    int t = dir ? (SS - 1 - step) : step;
    // issue zx loads early; latency hides under poll
    const u32* zxr = (const u32*)(zx + ((size_t)t*BB + eb)*G4 + wgi*32 + ec);
    u32 xi = zxr[0];
    u32 xf = zxr[256];
    u32 xg = zxr[512];
    u32 xo = zxr[768];
    f32x4 acc0 = {0.f,0.f,0.f,0.f}, acc1 = {0.f,0.f,0.f,0.f};
    if (step > 0) {
      int tp = dir ? t + 1 : t - 1;
      const char* gsrc = (const char*)(hbuf + (size_t)tp*BB*HH) + goff;
      u32x4 s0v, s1v, s2v, s3v;
      // per-thread data poll: all 16 dwords must be non-sentinel
      for (;;) {
        asm volatile("global_load_dwordx4 %0, %1, off sc0 sc1" : "=v"(s0v) : "v"(gsrc)     : "memory");
        asm volatile("global_load_dwordx4 %0, %1, off sc0 sc1" : "=v"(s1v) : "v"(gsrc+256) : "memory");
        asm volatile("global_load_dwordx4 %0, %1, off sc0 sc1" : "=v"(s2v) : "v"(gsrc+512) : "memory");
        asm volatile("global_load_dwordx4 %0, %1, off sc0 sc1" : "=v"(s3v) : "v"(gsrc+768) : "memory");
        asm volatile("s_waitcnt vmcnt(0)" ::: "memory");
        bool ok = s0v[0]!=SENT && s0v[1]!=SENT && s0v[2]!=SENT && s0v[3]!=SENT
               && s1v[0]!=SENT && s1v[1]!=SENT && s1v[2]!=SENT && s1v[3]!=SENT
               && s2v[0]!=SENT && s2v[1]!=SENT && s2v[2]!=SENT && s2v[3]!=SENT
               && s3v[0]!=SENT && s3v[1]!=SENT && s3v[2]!=SENT && s3v[3]!=SENT;
        if (ok) break;
        __builtin_amdgcn_s_sleep(1);
      }
      __builtin_amdgcn_sched_barrier(0);  // keep ds_writes below the validated loads
      *(u32x4*)(swrite)       = s0v;
      *(u32x4*)(swrite + 256) = s1v;
      *(u32x4*)(swrite + 512) = s2v;
      *(u32x4*)(swrite + 768) = s3v;
      __syncthreads();   // B2: stage visible
      #pragma unroll
      for (int kf = 0; kf < 16; ++kf) {
        bf16x8 a0 = *(const bf16x8*)(sread0 + kf*64);
        bf16x8 a1 = *(const bf16x8*)(sread1 + kf*64);
        acc0 = MFMA(a0, rb[kf], acc0);
        acc1 = MFMA(a1, rb[kf], acc1);
      }
    }
    int zc = ch*16 + (l & 15);
    int zb0 = (l >> 4) * 4;
    #pragma unroll
    for (int r = 0; r < 4; ++r) {
      zbuf[g][zc][zb0 + r] = acc0[r];
      zbuf[g][zc][16 + zb0 + r] = acc1[r];
    }
    __syncthreads();   // B3: gates exchanged
    float zi0 = zbuf[0][ec  ][eb] + bf2f((u16)(xi & 0xffffu));
    float zi1 = zbuf[0][ec+1][eb] + bf2f((u16)(xi >> 16));
    float zf0 = zbuf[1][ec  ][eb] + bf2f((u16)(xf & 0xffffu));
    float zf1 = zbuf[1][ec+1][eb] + bf2f((u16)(xf >> 16));
    float zg0 = zbuf[2][ec  ][eb] + bf2f((u16)(xg & 0xffffu));
    float zg1 = zbuf[2][ec+1][eb] + bf2f((u16)(xg >> 16));
    float zo0 = zbuf[3][ec  ][eb] + bf2f((u16)(xo & 0xffffu));
    float zo1 = zbuf[3][ec+1][eb] + bf2f((u16)(xo >> 16));
    c0 = sigm(zf0)*c0 + sigm(zi0)*tanh_f(zg0);
    c1 = sigm(zf1)*c1 + sigm(zi1)*tanh_f(zg1);
    float h0 = sigm(zo0)*tanh_f(c0);
    float h1 = sigm(zo1)*tanh_f(c1);
    u32 hpk = (u32)f2bf(h0) | ((u32)f2bf(h1) << 16);
    u32* hp = (u32*)(hbuf + ((size_t)t*BB + eb)*HH + wgi*32 + ec);
    asm volatile("global_store_dword %0, %1, off sc0 sc1" :: "v"(hp), "v"(hpk) : "memory");
    // producer never waits: RAW-only dependency, consumers validate data
  }
}

// ---------- phase C: h1 = [hf|hb] @ w1 + b1 ----------
__global__ __launch_bounds__(256) void k_dense(
    const u16* __restrict__ hf, const u16* __restrict__ hb,
    const u16* __restrict__ w1p, const float* __restrict__ b1,
    u16* __restrict__ h1)
{
  int mt = blockIdx.x, nt = blockIdx.y;
  int w = threadIdx.x >> 6, l = threadIdx.x & 63;
  int m0 = mt*128 + w*32;
  int r0 = m0 + (l & 15);
  const u16* f0 = hf + (size_t)r0*HH + (l >> 4)*8;
  const u16* f1 = hf + (size_t)(r0+16)*HH + (l >> 4)*8;
  const u16* g0 = hb + (size_t)r0*HH + (l >> 4)*8;
  const u16* g1 = hb + (size_t)(r0+16)*HH + (l >> 4)*8;
  f32x4 acc[2][8];
  #pragma unroll
  for (int i = 0; i < 2; ++i)
    #pragma unroll
    for (int j = 0; j < 8; ++j) acc[i][j] = (f32x4){0.f,0.f,0.f,0.f};
  const u16* bbase = w1p + ((size_t)(nt*8)*32)*512 + (size_t)l*8;
  for (int kf = 0; kf < 32; ++kf) {
    const u16* s0 = (kf < 16) ? (f0 + kf*32) : (g0 + (kf-16)*32);
    const u16* s1 = (kf < 16) ? (f1 + kf*32) : (g1 + (kf-16)*32);
    bf16x8 a0 = *(const bf16x8*)s0;
    bf16x8 a1 = *(const bf16x8*)s1;
    #pragma unroll
    for (int nf = 0; nf < 8; ++nf) {
      bf16x8 bv = *(const bf16x8*)(bbase + (size_t)(nf*32 + kf)*512);
      acc[0][nf] = MFMA(a0, bv, acc[0][nf]);
      acc[1][nf] = MFMA(a1, bv, acc[1][nf]);
    }
  }
  int cb = nt*128 + (l & 15);
  #pragma unroll
  for (int mi = 0; mi < 2; ++mi) {
    #pragma unroll
    for (int r = 0; r < 4; ++r) {
      int row = m0 + mi*16 + (l >> 4)*4 + r;
      #pragma unroll
      for (int nf = 0; nf < 8; ++nf) {
        int col = cb + nf*16;
        h1[(size_t)row*HH + col] = f2bf(acc[mi][nf][r] + b1[col]);
      }
    }
  }
}

// ---------- phase D: logits, softmax, probs, per-block NLL partials ----------
__global__ __launch_bounds__(256) void k_out(
    const u16* __restrict__ h1, const float* __restrict__ w2, const float* __restrict__ b2,
    const int* __restrict__ labels, float* __restrict__ out, float* __restrict__ part)
{
  int w = threadIdx.x >> 6, l = threadIdx.x & 63;
  float w2r[8][3];
  #pragma unroll
  for (int i = 0; i < 8; ++i)
    #pragma unroll
    for (int c = 0; c < 3; ++c) w2r[i][c] = w2[(l*8 + i)*3 + c];
  float b20 = b2[0], b21 = b2[1], b22 = b2[2];
  float nll = 0.f;
  int base = (blockIdx.x*4 + w)*16;
  for (int r = 0; r < 16; ++r) {
    int row = base + r;
    bf16x8 hv = *(const bf16x8*)(h1 + (size_t)row*HH + l*8);
    float s0 = 0.f, s1 = 0.f, s2 = 0.f;
    #pragma unroll
    for (int i = 0; i < 8; ++i) {
      float x = bf2f((u16)hv[i]);
      s0 += x*w2r[i][0]; s1 += x*w2r[i][1]; s2 += x*w2r[i][2];
    }
    #pragma unroll
    for (int off = 32; off > 0; off >>= 1) {
      s0 += __shfl_down(s0, off);
      s1 += __shfl_down(s1, off);
      s2 += __shfl_down(s2, off);
    }
    if (l == 0) {
      float l0 = s0+b20, l1 = s1+b21, l2 = s2+b22;
      float m = fmaxf(l0, fmaxf(l1, l2));
      float e0 = __expf(l0-m), e1 = __expf(l1-m), e2 = __expf(l2-m);
      float Z = e0+e1+e2, inv = 1.f/Z;
      int b = row & 31, s = row >> 5;
      float* po = out + ((size_t)b*SS + s)*3;
      po[0] = e0*inv; po[1] = e1*inv; po[2] = e2*inv;
      int lab = labels[b*SS + s];
      float ll = (lab == 0) ? l0 : (lab == 1 ? l1 : l2);
      nll += (m + __logf(Z)) - ll;
    }
  }
  __shared__ float ps[4];
  if (l == 0) ps[w] = nll;
  __syncthreads();
  if (threadIdx.x == 0) part[blockIdx.x] = ps[0]+ps[1]+ps[2]+ps[3];
}

__global__ void k_loss(const float* __restrict__ part, float* __restrict__ out) {
  __shared__ float sh[256];
  sh[threadIdx.x] = part[threadIdx.x];
  __syncthreads();
  for (int s = 128; s > 0; s >>= 1) {
    if (threadIdx.x < s) sh[threadIdx.x] += sh[threadIdx.x + s];
    __syncthreads();
  }
  if (threadIdx.x == 0) out[(size_t)MM*NC] = sh[0] / (float)BB;
}

extern "C" void kernel_launch(void* const* d_in, const int* in_sizes, int n_in,
                              void* d_out, int out_size, void* d_ws, size_t ws_size,
                              hipStream_t stream) {
  (void)in_sizes; (void)n_in; (void)out_size;
  const float* emb = (const float*)d_in[0];
  const float* fK  = (const float*)d_in[1];
  const float* fR  = (const float*)d_in[2];
  const float* fb  = (const float*)d_in[3];
  const float* bK  = (const float*)d_in[4];
  const float* bR  = (const float*)d_in[5];
  const float* bb  = (const float*)d_in[6];
  const float* w1  = (const float*)d_in[7];
  const float* b1  = (const float*)d_in[8];
  const float* w2  = (const float*)d_in[9];
  const float* b2  = (const float*)d_in[10];
  const int* ids   = (const int*)d_in[11];
  const int* prior = (const int*)d_in[12];
  const int* labels= (const int*)d_in[13];

  size_t off = 0;
  auto take = [&](size_t bytes) -> char* {
    char* p = (char*)d_ws + off;
    off += (bytes + 255) & ~(size_t)255;
    return p;
  };
  u16* embT = (u16*)take((size_t)VV*EE*2);
  u16* Kfp  = (u16*)take((size_t)EE*G4*2);
  u16* Kbp  = (u16*)take((size_t)EE*G4*2);
  u16* Rfp  = (u16*)take((size_t)HH*G4*2);
  u16* Rbp  = (u16*)take((size_t)HH*G4*2);
  u16* w1p  = (u16*)take((size_t)(2*HH)*HH*2);
  u16* zxf  = (u16*)take((size_t)MM*G4*2);
  u16* zxb  = (u16*)take((size_t)MM*G4*2);
  u16* hf   = (u16*)take((size_t)MM*HH*2);
  u16* hb   = (u16*)take((size_t)MM*HH*2);
  u16* h1   = (u16*)take((size_t)MM*HH*2);
  float* part = (float*)take(256*4);
  if (off > ws_size) return;

  // sentinel-fill h buffers (every launch: replays must re-arm the sync)
  hipMemsetAsync(hf, 0xFF, (size_t)MM*HH*2, stream);
  hipMemsetAsync(hb, 0xFF, (size_t)MM*HH*2, stream);
  k_conv<<<12000, 256, 0, stream>>>(emb, embT, VV*EE/8);
  k_pack<<<768, 256, 0, stream>>>(fK, Kfp, EE, G4);
  k_pack<<<768, 256, 0, stream>>>(bK, Kbp, EE, G4);
  k_pack<<<512, 256, 0, stream>>>(fR, Rfp, HH, G4);
  k_pack<<<512, 256, 0, stream>>>(bR, Rbp, HH, G4);
  k_pack<<<256, 256, 0, stream>>>(w1, w1p, 2*HH, HH);
  k_proj<<<dim3(128,32), 256, 0, stream>>>(embT, Kfp, Kbp, fb, bb, fK, bK, ids, prior, zxf, zxb);
  k_scan<<<32, 512, 0, stream>>>(zxf, zxb, Rfp, Rbp, hf, hb);
  k_dense<<<dim3(128,4), 256, 0, stream>>>(hf, hb, w1p, b1, h1);
  k_out<<<256, 256, 0, stream>>>(h1, w2, b2, labels, (float*)d_out, part);
  k_loss<<<1, 256, 0, stream>>>(part, (float*)d_out);
}